// Round 1
// baseline (398.567 us; speedup 1.0000x reference)
//
#include <hip/hip_runtime.h>

typedef _Float16 f16x8 __attribute__((ext_vector_type(8)));
typedef float    f32x4 __attribute__((ext_vector_type(4)));

constexpr int BATCH = 2048;
constexpr int SEQ   = 512;
constexpr int H     = 50;
constexpr int NB    = 4;     // batch per block -> 512 blocks = 2 blocks per CU
constexpr int NT    = 512;   // 8 waves, 2 per SIMD per block; 2 blocks -> 4/SIMD
constexpr int KQ    = 4;     // panel k-chunks of 32 (K=128)
constexpr int PSZ   = KQ * 64 * 8;   // panel halfs (2048 = 4 KB)

__device__ __forceinline__ float fexp2(float x) { return __builtin_amdgcn_exp2f(x); }
__device__ __forceinline__ float frcp(float x)  { return __builtin_amdgcn_rcpf(x); }
__device__ __forceinline__ _Float16 f16hi(float w) { return (_Float16)w; }
__device__ __forceinline__ _Float16 f16lo(float w) {
    _Float16 h = (_Float16)w; return (_Float16)(w - (float)h);
}
// B-panel frag-linear address (halfs) for value (k, n), k<128, n<16
__device__ __forceinline__ int baddr(int k, int n) {
    return (((k >> 5) * 64) + (((k >> 3) & 3) * 16) + n) * 8 + (k & 7);
}
union H2U { unsigned u; _Float16 h[2]; };

constexpr float K1 = 1.4426950408889634f;   // log2(e)
constexpr float K2 = 2.8853900817779268f;   // 2*log2(e)

// === 2-blocks-per-CU restructure (r10) ===
// NB=4 -> 512 blocks -> 2 independent barrier groups per CU; their lockstep
// recurrences drift and mutually hide the post-barrier ds_read bubble, the
// dependent-MFMA chains and the serial trans (exp/rcp) chain that the old
// 1-block/CU kernel exposed (VALU 49% + MFMA 25% + ~30% stall).
//
// Panel k-map unchanged (HI-ONLY f16, 4 chunks):
//   k [0,50): h1 unit j=k   | k 50,51: x_hi,x_lo | k [52,64): 0
//   k [64,114): h2 unit j=k-64                   | k [114,128): 0
// Columns: col n carries batch (n&3) -- FOUR copies of each batch so that
// after MFMA each lane owns one chain:
//   lane(quad,nn): hiT=nn>>3 (tile), hiL=(nn>>2)&1 (layer), col=nn&3 (batch)
// Wave w (w<7) owns tiles m0=2w, m1=2w+1 (wave6 m1 dead); wave 7 stages x.
// Each wave: 4 accumulators (t0/t1 x L0/L1) = chains of 2,4,2,4 MFMAs (good
// ILP), then a 12-cndmask select routes the right g to each lane's chain.
// h written to 4 column copies (one addr + imm offsets +64/128/192 B).
// Schedule (1 barrier/step): iter s reads sB[s&1] = {h1(s-1), x(s), h2(s-2)},
// writes sB[(s+1)&1] = {h1(s), x(s+1), h2(s-1)}; edges s=0,511,512 peeled.
// Numerics identical to r9-hi (absmax ~2^-11).

__global__ __launch_bounds__(NT, 4) void lstm2_hi(
    const float* __restrict__ x,
    const float* __restrict__ Wih0, const float* __restrict__ Whh0,
    const float* __restrict__ bih0, const float* __restrict__ bhh0,
    const float* __restrict__ Wih1, const float* __restrict__ Whh1,
    const float* __restrict__ bih1, const float* __restrict__ bhh1,
    const float* __restrict__ fcW,  const float* __restrict__ fcb,
    float* __restrict__ out)
{
    __shared__ _Float16 sB[2][PSZ];     // double-buffered panel, 8 KB
    __shared__ unsigned sXu[SEQ * NB];  // pre-split x (hi,lo), 8 KB
    __shared__ float    sH2f[H * NB];   // final h2

    const int t    = threadIdx.x;
    const int wave = t >> 6, lane = t & 63;
    const int quad = lane >> 4, nn = lane & 15;
    const int bbase = blockIdx.x * NB;

    // zero both panels (pads must stay 0 forever)
    for (int i = t; i < 2 * PSZ; i += NT) ((_Float16*)sB)[i] = (_Float16)0.f;

    // ---- pre-stage ALL x as packed f16 hi/lo pairs (coalesced) ----
    for (int i = t; i < NB * SEQ; i += NT) {
        const int b = i >> 9, s = i & (SEQ - 1);
        float xv = x[(bbase + b) * SEQ + s];
        H2U p; p.h[0] = f16hi(xv); p.h[1] = f16lo(xv);
        sXu[s * NB + b] = p.u;
    }

    // ---- constant A-fragments; wave w owns tiles 2w, 2w+1 ----
    const bool mmv = (wave < 7);
    const int  m0  = 2 * wave, m1 = 2 * wave + 1;
    const bool m1v = mmv && (4 * m1 < H + 3);   // tile 13 fully dead

    f16x8 a0[2][2];       // [tile][chunk] L0: chunks 0..1 (K=64)
    f16x8 a1[2][KQ];      // [tile][chunk] L1: chunks 0..3 (K=128)
    f32x4 bias[2][2];     // [tile][layer]
    #pragma unroll
    for (int tt = 0; tt < 2; ++tt) { bias[tt][0] = f32x4{0,0,0,0}; bias[tt][1] = f32x4{0,0,0,0}; }

    if (mmv) {
        #pragma unroll
        for (int tt = 0; tt < 2; ++tt) {
            const int  m    = tt ? m1 : m0;
            const int  jr   = m * 4 + (nn >> 2);     // hidden unit of A phys row nn
            const int  gate = nn & 3;
            const bool rv   = (jr < H);
            const int  lrow = gate * H + jr;         // logical W row
            #pragma unroll
            for (int q = 0; q < 2; ++q) {
                #pragma unroll
                for (int j = 0; j < 8; ++j) {
                    const int k = q * 32 + quad * 8 + j;
                    _Float16 v = (_Float16)0.f;
                    if (rv) {
                        if      (k < 50)   v = (_Float16)Whh0[lrow * H + k];
                        else if (k == 50)  v = f16hi(Wih0[lrow]);
                        else if (k == 51)  v = f16lo(Wih0[lrow]);
                    }
                    a0[tt][q][j] = v;
                }
            }
            #pragma unroll
            for (int q = 0; q < KQ; ++q) {
                #pragma unroll
                for (int j = 0; j < 8; ++j) {
                    const int k = q * 32 + quad * 8 + j;
                    _Float16 v = (_Float16)0.f;
                    if (rv) {
                        if      (k < 50)              v = (_Float16)Wih1[lrow * H + k];
                        else if (k >= 64 && k < 114)  v = (_Float16)Whh1[lrow * H + (k - 64)];
                    }
                    a1[tt][q][j] = v;
                }
            }
            const int jq = m * 4 + quad;
            const bool bv = (jq < H);
            #pragma unroll
            for (int r = 0; r < 4; ++r) {
                bias[tt][0][r] = bv ? (bih0[r * H + jq] + bhh0[r * H + jq]) : 0.f;
                bias[tt][1][r] = bv ? (bih1[r * H + jq] + bhh1[r * H + jq]) : 0.f;
            }
        }
    }

    // per-lane chain identity: tile = hiT, layer = hiL, batch = col
    const int  hiT  = nn >> 3;
    const int  hiL  = (nn >> 2) & 1;
    const int  col  = nn & 3;
    const int  jj   = (hiT ? m1 : m0) * 4 + quad;   // hidden unit (valid < 50)
    const int  kb   = hiL ? (64 + jj) : jj;         // this lane's h row in panel
    const int  wH   = baddr(kb, col);               // half slot, column copy 0
    const bool wrOK = mmv && (jj < H);
    float c = 0.f;                                  // c-state of this lane's chain

    // x-staging lane constants (wave 7, lanes 0..15 cover all 16 cols)
    const int xcol = lane & 3;
    const int xad  = baddr(50, lane & 15) >> 1;     // u32 idx

    __syncthreads();
    if (t < 16)                                     // x(0), all 4 column copies
        ((unsigned*)sB[0])[baddr(50, t) >> 1] = sXu[t & 3];
    __syncthreads();

    auto body = [&](int s, const _Float16* __restrict__ br,
                    _Float16* __restrict__ bw,
                    bool doL0, bool doL1, bool doX, bool last) {
        if (mmv) {
            f16x8 bq[KQ];
            #pragma unroll
            for (int q = 0; q < KQ; ++q)
                bq[q] = *(const f16x8*)&br[(q * 64 + lane) * 8];

            f32x4 g00 = bias[0][0];
            #pragma unroll
            for (int q = 0; q < 2; ++q)
                g00 = __builtin_amdgcn_mfma_f32_16x16x32_f16(a0[0][q], bq[q], g00, 0, 0, 0);
            f32x4 g01 = bias[0][1];
            #pragma unroll
            for (int q = 0; q < KQ; ++q)
                g01 = __builtin_amdgcn_mfma_f32_16x16x32_f16(a1[0][q], bq[q], g01, 0, 0, 0);
            f32x4 g10 = bias[1][0];
            f32x4 g11 = bias[1][1];
            if (m1v) {
                #pragma unroll
                for (int q = 0; q < 2; ++q)
                    g10 = __builtin_amdgcn_mfma_f32_16x16x32_f16(a0[1][q], bq[q], g10, 0, 0, 0);
                #pragma unroll
                for (int q = 0; q < KQ; ++q)
                    g11 = __builtin_amdgcn_mfma_f32_16x16x32_f16(a1[1][q], bq[q], g11, 0, 0, 0);
            }

            f32x4 g;
            #pragma unroll
            for (int r = 0; r < 4; ++r) {
                const float ga = hiT ? g10[r] : g00[r];
                const float gb = hiT ? g11[r] : g01[r];
                g[r] = hiL ? gb : ga;
            }

            const bool act = hiL ? doL1 : doL0;
            if (act) {
                float Ei = fexp2(-K1 * g[0]);
                float Ef = fexp2(-K1 * g[1]);
                float Eg = fexp2(-K2 * fabsf(g[2]));
                float Eo = fexp2(-K1 * g[3]);
                float it = copysignf((1.f - Eg) * frcp((1.f + Ei) * (1.f + Eg)), g[2]);
                c = frcp(1.f + Ef) * c + it;
                float Ec = fexp2(-K2 * fabsf(c));
                float h  = copysignf((1.f - Ec) * frcp((1.f + Eo) * (1.f + Ec)), c);
                if (wrOK) {
                    if (last && hiL) {
                        sH2f[jj * NB + col] = h;        // h2(511) for the FC
                    } else {
                        _Float16 hh = (_Float16)h;
                        bw[wH]      = hh;               // 4 column copies,
                        bw[wH + 32] = hh;               // one addr + imm offsets
                        bw[wH + 64] = hh;
                        bw[wH + 96] = hh;
                    }
                }
            }
        } else if (doX && lane < 16) {
            ((unsigned*)bw)[xad] = sXu[(s + 1) * NB + xcol];
        }
        __syncthreads();   // the ONLY barrier per step
    };

    body(0, sB[0], sB[1], true, false, true, false);
    #pragma unroll 1
    for (int i = 0; i < 255; ++i) {
        body(2 * i + 1, sB[1], sB[0], true, true, true, false);
        body(2 * i + 2, sB[0], sB[1], true, true, true, false);
    }
    body(511, sB[1], sB[0], true, true, false, false);
    body(512, sB[0], sB[1], false, true, false, true);

    // ---- FC epilogue: out[b] = fcW . h2_last[b] + fcb ----
    if (t < NB) {
        float sum = fcb[0];
        #pragma unroll
        for (int jx = 0; jx < H; ++jx) sum += fcW[jx] * sH2f[jx * NB + t];
        out[bbase + t] = sum;
    }
}

extern "C" void kernel_launch(void* const* d_in, const int* in_sizes, int n_in,
                              void* d_out, int out_size, void* d_ws, size_t ws_size,
                              hipStream_t stream)
{
    const float* x    = (const float*)d_in[0];
    const float* Wih0 = (const float*)d_in[1];
    const float* Whh0 = (const float*)d_in[2];
    const float* bih0 = (const float*)d_in[3];
    const float* bhh0 = (const float*)d_in[4];
    const float* Wih1 = (const float*)d_in[5];
    const float* Whh1 = (const float*)d_in[6];
    const float* bih1 = (const float*)d_in[7];
    const float* bhh1 = (const float*)d_in[8];
    const float* fcW  = (const float*)d_in[9];
    const float* fcb  = (const float*)d_in[10];

    lstm2_hi<<<BATCH / NB, NT, 0, stream>>>(
        x, Wih0, Whh0, bih0, bhh0, Wih1, Whh1, bih1, bhh1, fcW, fcb,
        (float*)d_out);
}

// Round 2
// 333.159 us; speedup vs baseline: 1.1963x; 1.1963x over previous
//
#include <hip/hip_runtime.h>

typedef _Float16 f16x8 __attribute__((ext_vector_type(8)));
typedef float    f32x4 __attribute__((ext_vector_type(4)));

constexpr int BATCH = 2048;
constexpr int SEQ   = 512;
constexpr int H     = 50;
constexpr int NB    = 8;     // batch per block -> 256 blocks = 1 per CU
constexpr int NT    = 1024;  // 16 waves, 4 per SIMD
constexpr int KQ    = 5;     // panel k-chunks of 32 (K=160)
constexpr int PSZ   = KQ * 64 * 8;   // panel halfs (2560 = 5 KB)

__device__ __forceinline__ float fexp2(float x) { return __builtin_amdgcn_exp2f(x); }
__device__ __forceinline__ float frcp(float x)  { return __builtin_amdgcn_rcpf(x); }
// B-panel frag-linear address (halfs) for value (k, n), k<160, n<16
__device__ __forceinline__ int baddr(int k, int n) {
    return (((k >> 5) * 64) + (((k >> 3) & 3) * 16) + n) * 8 + (k & 7);
}

constexpr float K1 = 1.4426950408889634f;   // log2(e)
constexpr float K2 = 2.8853900817779268f;   // 2*log2(e)

// === r11: merged-A single-chain (revert r10's 2-block split; keep r9 frame) ===
// Panel k-map (f16, 5 chunks, K=160):
//   k [0,50):    h1 unit j=k        -- nonzero in cols 0..7 ONLY (L0 columns)
//   k [50,100):  h1 COPY j=k-50     -- nonzero in cols 8..15 ONLY (L1 columns)
//   k [100,150): h2 unit j=k-100    -- cols 8..15 ONLY
//   k [150,160): zero pad
// A (per 16-row gate-perm tile, shared by all columns):
//   k<50: Whh0 | k in [50,100): Wih1 | k in [100,150): Whh1 | else 0
// Because A's L0/L1 supports are k-disjoint and B zeroes the foreign k-rows
// per column group, ONE accumulator chain (split 3+2 for latency) yields the
// correct per-column layer result -> the r9 per-step 4-cndmask join on the
// 4-deep L1 chain is gone, and MFMA/wave drops 6 -> 5.
// x (INPUT_SIZE=1) leaves the MFMA: g[r] += Wih0[r*H+jj] * x(s,col) as exact
// f32 fma on the owning lane (weights zeroed on L1 lanes). No x rows, no
// x-staging wave, better precision than the old hi/lo f16 split.
// GATE PERM unchanged: tile m phys row w <-> jj=4m+(w>>2), gate w&3; lane
// (quad,nn) reg r = gate r of unit jj=4m+quad; col=nn&7; hiL=nn>=8 -> layer.
// Schedule (1 barrier/step): iter s reads sB[s&1] = {h1(s-1), h2(s-2)},
// writes sB[(s+1)&1] = {h1(s), h2(s-1)}; edges s=0,511,512 peeled.
// Numerics: L0 bit-identical to r9 (zero-row chunks add exact 0); L1 only
// reassociates the same f32 terms. absmax ~2^-11 expected unchanged.

__global__ __launch_bounds__(NT, 4) void lstm2_hi(
    const float* __restrict__ x,
    const float* __restrict__ Wih0, const float* __restrict__ Whh0,
    const float* __restrict__ bih0, const float* __restrict__ bhh0,
    const float* __restrict__ Wih1, const float* __restrict__ Whh1,
    const float* __restrict__ bih1, const float* __restrict__ bhh1,
    const float* __restrict__ fcW,  const float* __restrict__ fcb,
    float* __restrict__ out)
{
    __shared__ _Float16 sB[2][PSZ];     // double-buffered panel, 10 KB
    __shared__ float    sXf[SEQ * NB];  // pre-staged x (exact f32), 16 KB
    __shared__ float    sH2f[H * NB];   // final h2

    const int t    = threadIdx.x;
    const int wave = t >> 6, lane = t & 63;
    const int quad = lane >> 4, nn = lane & 15;
    const int bbase = blockIdx.x * NB;

    // zero both panels (pads and foreign-column regions must stay 0 forever)
    for (int i = t; i < 2 * PSZ; i += NT) ((_Float16*)sB)[i] = (_Float16)0.f;

    // ---- pre-stage ALL x as f32 (coalesced along s) ----
    for (int i = t; i < NB * SEQ; i += NT) {
        const int b = i >> 9, s = i & (SEQ - 1);
        sXf[s * NB + b] = x[(bbase + b) * SEQ + s];
    }

    // ---- constant merged A-fragments; wave w owns tile m = w (13 active) ----
    const bool mmv = (wave < 13);
    f16x8 am[KQ];                      // merged A: 5 chunks (K=160)
    f32x4 biasv = {0, 0, 0, 0};        // per-lane (layer-selected) bias
    float wxv[4] = {0, 0, 0, 0};       // per-lane x weights (0 on L1 lanes)

    // per-lane chain identity: layer = hiL, batch = col
    const int  hiL  = nn >> 3;
    const int  col  = nn & 7;
    const int  jj   = wave * 4 + quad;             // hidden unit (valid < 50)
    const bool jv   = mmv && (jj < H);

    if (mmv) {
        const int  m    = wave;
        const int  jr   = m * 4 + (nn >> 2);       // hidden unit of A phys row nn
        const int  gate = nn & 3;
        const bool rv   = (jr < H);
        const int  lrow = gate * H + jr;           // logical W row
        #pragma unroll
        for (int q = 0; q < KQ; ++q) {
            #pragma unroll
            for (int j = 0; j < 8; ++j) {
                const int k = q * 32 + quad * 8 + j;
                _Float16 v = (_Float16)0.f;
                if (rv) {
                    if      (k < 50)               v = (_Float16)Whh0[lrow * H + k];
                    else if (k >= 50 && k < 100)   v = (_Float16)Wih1[lrow * H + (k - 50)];
                    else if (k >= 100 && k < 150)  v = (_Float16)Whh1[lrow * H + (k - 100)];
                }
                am[q][j] = v;
            }
        }
        if (jv) {
            #pragma unroll
            for (int r = 0; r < 4; ++r) {
                biasv[r] = hiL ? (bih1[r * H + jj] + bhh1[r * H + jj])
                               : (bih0[r * H + jj] + bhh0[r * H + jj]);
                wxv[r]   = hiL ? 0.f : Wih0[r * H + jj];
            }
        }
    }

    // h write slots (lane constants)
    const int wA  = hiL ? baddr(100 + jj, col + 8)   // h2 row
                        : baddr(jj, col);            // h1 row, L0 copy
    const int wB  = baddr(50 + jj, col + 8);         // h1 row, L1 copy (lo only)
    const bool wrOK = jv;
    float c = 0.f;                                   // c0 (lo) or c1 (hi)

    __syncthreads();

    auto body = [&](int s, const _Float16* __restrict__ br,
                    _Float16* __restrict__ bw,
                    bool doL0, bool doL1, bool last) {
        if (mmv) {
            const int sidx = (s < SEQ) ? s : 0;      // clamp (value unused at 512)
            const float xv = sXf[sidx * NB + col];   // broadcast read

            f16x8 bq[KQ];
            #pragma unroll
            for (int q = 0; q < KQ; ++q)
                bq[q] = *(const f16x8*)&br[(q * 64 + lane) * 8];

            // single merged chain, split 3+2 for latency
            f32x4 gA = biasv;
            #pragma unroll
            for (int q = 0; q < 3; ++q)
                gA = __builtin_amdgcn_mfma_f32_16x16x32_f16(am[q], bq[q], gA, 0, 0, 0);
            f32x4 gB = {0, 0, 0, 0};
            #pragma unroll
            for (int q = 3; q < KQ; ++q)
                gB = __builtin_amdgcn_mfma_f32_16x16x32_f16(am[q], bq[q], gB, 0, 0, 0);

            float g[4];
            #pragma unroll
            for (int r = 0; r < 4; ++r) g[r] = fmaf(wxv[r], xv, gA[r] + gB[r]);

            const bool act = hiL ? doL1 : doL0;
            if (act) {
                float Ei = fexp2(-K1 * g[0]);
                float Ef = fexp2(-K1 * g[1]);
                float Eg = fexp2(-K2 * fabsf(g[2]));
                float Eo = fexp2(-K1 * g[3]);
                float it = copysignf((1.f - Eg) * frcp((1.f + Ei) * (1.f + Eg)), g[2]);
                c = frcp(1.f + Ef) * c + it;
                float Ec = fexp2(-K2 * fabsf(c));
                float h  = copysignf((1.f - Ec) * frcp((1.f + Eo) * (1.f + Ec)), c);
                if (wrOK) {
                    if (last && hiL) {
                        sH2f[jj * NB + col] = h;     // h2(511) for the FC
                    } else {
                        _Float16 hh = (_Float16)h;
                        bw[wA] = hh;                 // own-layer slot
                        if (!hiL) bw[wB] = hh;       // h1 copy for L1 columns
                    }
                }
            }
        }
        __syncthreads();   // the ONLY barrier per step
    };

    body(0, sB[0], sB[1], true, false, false);
    #pragma unroll 1
    for (int i = 0; i < 255; ++i) {
        body(2 * i + 1, sB[1], sB[0], true, true, false);
        body(2 * i + 2, sB[0], sB[1], true, true, false);
    }
    body(511, sB[1], sB[0], true, true, false);
    body(512, sB[0], sB[1], false, true, true);

    // ---- FC epilogue: out[b] = fcW . h2_last[b] + fcb ----
    if (t < NB) {
        float sum = fcb[0];
        #pragma unroll
        for (int jx = 0; jx < H; ++jx) sum += fcW[jx] * sH2f[jx * NB + t];
        out[bbase + t] = sum;
    }
}

extern "C" void kernel_launch(void* const* d_in, const int* in_sizes, int n_in,
                              void* d_out, int out_size, void* d_ws, size_t ws_size,
                              hipStream_t stream)
{
    const float* x    = (const float*)d_in[0];
    const float* Wih0 = (const float*)d_in[1];
    const float* Whh0 = (const float*)d_in[2];
    const float* bih0 = (const float*)d_in[3];
    const float* bhh0 = (const float*)d_in[4];
    const float* Wih1 = (const float*)d_in[5];
    const float* Whh1 = (const float*)d_in[6];
    const float* bih1 = (const float*)d_in[7];
    const float* bhh1 = (const float*)d_in[8];
    const float* fcW  = (const float*)d_in[9];
    const float* fcb  = (const float*)d_in[10];

    lstm2_hi<<<BATCH / NB, NT, 0, stream>>>(
        x, Wih0, Whh0, bih0, bhh0, Wih1, Whh1, bih1, bhh1, fcW, fcb,
        (float*)d_out);
}